// Round 10
// baseline (481.561 us; speedup 1.0000x reference)
//
#include <hip/hip_runtime.h>
#include <hip/hip_bf16.h>

// Problem constants (fixed by reference)
#define N_PER    4096
#define KNBR     16
#define NTOT     32768
#define D_IN     32
#define D_H      64
#define D_OUT    128
#define E_TOT    (NTOT * KNBR)            // 524288

#define OUT1_OFF (NTOT * D_OUT)           // pos output offset (elements)
#define OUT2_OFF (NTOT * D_OUT + NTOT*3)  // batch output offset (elements)

#define KNN_INF 3.4e38f

typedef __attribute__((ext_vector_type(8))) short bf16x8;   // MFMA A/B frag
typedef __attribute__((ext_vector_type(4))) float f32x4;    // MFMA C/D frag
union U16 { uint4 u; bf16x8 v; };                           // legal type-pun

// ---------------------------------------------------------------------------
// Static device scratch; every buffer fully (re)written each call.
// ---------------------------------------------------------------------------
__device__ int            g_dtflag;               // 1 = bf16 storage
__device__ float          g_posf[NTOT * 3];       // f32 pos (exact bf16 upconvert)
__device__ float          g_scf[NTOT];            // per-node |p|^2 (unfused, = numpy sq)
__device__ float4         g_pos4[NTOT];           // {-2px,-2py,-2pz, |p|^2} packed (scan2)
__device__ uint4          g_nbB[NTOT];            // bf16 B-frag source {-2p, sc_hi, sc_lo}
__device__ int            g_nbr[E_TOT];
__device__ unsigned short g_base1h[NTOT * D_H];   // bf16 base1
__device__ uint4          g_Bfrag[2 * 4 * 64];    // W2 B-fragments [ks][nt][lane]
__device__ float          g_Wd[3 * D_H];
__device__ float          g_fb2v[D_H];
__device__ int            g_cnt[NTOT];
__device__ int            g_bsum[NTOT / 256];     // per-block cnt sums (scan)
__device__ int            g_offs[NTOT + 1];
__device__ int            g_cursor[NTOT];
__device__ int            g_inlist[E_TOT];
__device__ float          g_agg[NTOT * D_H];      // zero-inited (atomicMax targets)

__device__ __forceinline__ float ldf(const void* p, int i, int bf) {
    if (bf) return __uint_as_float(((unsigned)((const unsigned short*)p)[i]) << 16);
    return ((const float*)p)[i];
}
__device__ __forceinline__ unsigned bf16rne(float f) {
    unsigned u = __float_as_uint(f);
    return (u + 0x7FFFu + ((u >> 16) & 1u)) >> 16;
}
__device__ __forceinline__ void stf(void* p, int i, float v, int bf) {
    if (bf) ((unsigned short*)p)[i] = (unsigned short)bf16rne(v);
    else    ((float*)p)[i] = v;
}
__device__ __forceinline__ float b2f(unsigned short h) {
    return __uint_as_float(((unsigned)h) << 16);
}
// Inline dtype probe: majority vote over 64 words of a float tensor.
__device__ __forceinline__ int wave_probe(const void* x) {
    unsigned wv = ((const unsigned*)x)[threadIdx.x & 63];
    unsigned e = (wv >> 7) & 0xFFu;
    unsigned long long mk = __ballot(e >= 110u && e <= 140u);
    return (__popcll(mk) >= 32) ? 1 : 0;
}

// ---------------------------------------------------------------------------
// prep: blocks 0..1023    = pos->f32, |p|^2, {-2p,sc} float4, bf16 B-frag src,
//                           zero cnt/agg
//       blocks 1024..2047 = base1[n][d] (vectorized dual-dtype x loads)
//       block  2048       = stage edge-kernel weights + dtype flag
// ---------------------------------------------------------------------------
__global__ __launch_bounds__(256) void prep_kernel(const void* __restrict__ x,
                                                   const void* __restrict__ pos,
                                                   const void* __restrict__ fW1,
                                                   const void* __restrict__ fb1,
                                                   const void* __restrict__ fW2,
                                                   const void* __restrict__ fb2) {
    const int bf = wave_probe(x);
    const int b = blockIdx.x;
    if (b < 1024) {
        const int i0 = b * 256 + threadIdx.x;
        const int stride = 1024 * 256;
        for (int i = i0; i < NTOT * 3; i += stride) g_posf[i] = ldf(pos, i, bf);
        {
#pragma clang fp contract(off)
            for (int i = i0; i < NTOT; i += stride) {
                float a = ldf(pos, i * 3 + 0, bf);
                float c2 = ldf(pos, i * 3 + 1, bf);
                float c3 = ldf(pos, i * 3 + 2, bf);
                float sc = a * a + c2 * c2 + c3 * c3;
                g_scf[i] = sc;
                g_pos4[i] = make_float4(-2.0f * a, -2.0f * c2, -2.0f * c3, sc);
                unsigned xh = bf16rne(-2.0f * a);
                unsigned yh = bf16rne(-2.0f * c2);
                unsigned zh = bf16rne(-2.0f * c3);
                unsigned sh = bf16rne(sc);
                float slo = sc - b2f((unsigned short)sh);
                unsigned sl = bf16rne(slo);
                g_nbB[i] = make_uint4(xh | (yh << 16), zh | (sh << 16), sl, 0u);
                g_cnt[i] = 0;
            }
        }
        for (int i = i0; i < NTOT * D_H; i += stride) g_agg[i] = 0.0f;
    } else if (b < 2048) {
        int lane = threadIdx.x & 63, wid = threadIdx.x >> 6;
        int n0 = (b - 1024) * 32 + wid * 8;
        float wcol[D_IN];
#pragma unroll
        for (int k = 0; k < D_IN; k++) wcol[k] = ldf(fW1, k * D_H + lane, bf);
        float bb = ldf(fb1, lane, bf);
        if (bf) {
            const unsigned short* xp = (const unsigned short*)x;
            for (int r = 0; r < 8; r++) {
                int n = n0 + r;
                const uint4* xr = (const uint4*)(xp + (size_t)n * D_IN);
                float acc = bb;
#pragma unroll
                for (int q4 = 0; q4 < 4; q4++) {
                    uint4 w4 = xr[q4];
                    unsigned ww[4] = {w4.x, w4.y, w4.z, w4.w};
#pragma unroll
                    for (int p = 0; p < 4; p++) {
                        int k = q4 * 8 + p * 2;
                        acc += __uint_as_float(ww[p] << 16) * wcol[k];
                        acc += __uint_as_float(ww[p] & 0xFFFF0000u) * wcol[k + 1];
                    }
                }
                g_base1h[(size_t)n * D_H + lane] = (unsigned short)bf16rne(acc);
            }
        } else {
            const float* xp = (const float*)x;
            for (int r = 0; r < 8; r++) {
                int n = n0 + r;
                const float4* xr = (const float4*)(xp + (size_t)n * D_IN);
                float acc = bb;
#pragma unroll
                for (int q4 = 0; q4 < 8; q4++) {
                    float4 w4 = xr[q4];
                    int k = q4 * 4;
                    acc += w4.x * wcol[k] + w4.y * wcol[k + 1] + w4.z * wcol[k + 2] + w4.w * wcol[k + 3];
                }
                g_base1h[(size_t)n * D_H + lane] = (unsigned short)bf16rne(acc);
            }
        }
    } else {
        if (threadIdx.x == 0) g_dtflag = bf;
        for (int t = threadIdx.x; t < 3 * D_H; t += 256) g_Wd[t] = ldf(fW1, D_IN * D_H + t, bf);
        if (threadIdx.x < D_H) g_fb2v[threadIdx.x] = ldf(fb2, threadIdx.x, bf);
        for (int idx = threadIdx.x; idx < 512; idx += 256) {
            int lane = idx & 63, nt = (idx >> 6) & 3, ks = idx >> 8;
            int n = nt * 16 + (lane & 15);
            int k0 = ks * 32 + ((lane >> 4) << 3);
            unsigned wds[4];
#pragma unroll
            for (int jp = 0; jp < 4; jp++) {
                unsigned lo = bf16rne(ldf(fW2, (k0 + 2 * jp) * D_H + n, bf));
                unsigned hi = bf16rne(ldf(fW2, (k0 + 2 * jp + 1) * D_H + n, bf));
                wds[jp] = lo | (hi << 16);
            }
            g_Bfrag[idx] = make_uint4(wds[0], wds[1], wds[2], wds[3]);
        }
    }
}

// ---------------------------------------------------------------------------
// KNN + fused in-degree count. MFMA scan1 (as round 9, with union puns) BUT
// correctness no longer depends on T being right:
//  scan2 counts survivors at two thresholds, T and Ts = T - gap (gap=1e-4).
//  Fast path requires cnt_strict >= 16 (and cnt <= 64). Proof of exactness:
//    cnt_strict>=16  =>  d16_fma <= T-gap. For any exact-top-16 c:
//    d_fma(c) <= d16_exact'+eps <= d16_fma+2eps <= T-gap+2eps < T  (2eps~2e-5)
//    => all true top-16 survive => exact unfused (d,idx) sort is exact.
//  Otherwise: exact slow path (independent of T). So a wrong T can only cost
//  time, never correctness.
// ---------------------------------------------------------------------------
__global__ __launch_bounds__(512) void knn_kernel() {
#pragma clang fp contract(off)
    __shared__ __align__(16) float s_part[8192];   // 32KB: scan1 partials, then scan2 float4 staging
    __shared__ int s_i[8][8][64];                  // 16KB survivor indices
    float4* s_c4 = (float4*)s_part;
    const int lane = threadIdx.x & 63;
    const int wid  = threadIdx.x >> 6;
    const int quad = lane >> 4;
    const int l15  = lane & 15;
    const int qblk  = blockIdx.x * 64;
    const int qbase = qblk + wid * 8;
    const int cbase = (qblk >> 12) << 12;
    const float* cp  = g_posf + cbase * 3;
    const float* csc = g_scf + cbase;
    const float margin = g_dtflag ? 2e-3f : 0.05f;
    const float gap = 1e-4f;

    float qx[8], qy[8], qz[8], qs[8];
#pragma unroll
    for (int r = 0; r < 8; r++) {
        qx[r] = g_posf[(qbase + r) * 3 + 0];
        qy[r] = g_posf[(qbase + r) * 3 + 1];
        qz[r] = g_posf[(qbase + r) * 3 + 2];
        qs[r] = g_scf[qbase + r];
    }

    // ---- scan 1 (MFMA): wave's 512-cand segment vs all 64 block queries ----
    bf16x8 afrag[4];
#pragma unroll
    for (int mt = 0; mt < 4; mt++) {
        int q = qblk + mt * 16 + l15;
        unsigned w0 = bf16rne(g_posf[q * 3 + 0]) | (bf16rne(g_posf[q * 3 + 1]) << 16);
        unsigned w1 = bf16rne(g_posf[q * 3 + 2]) | (0x3F80u << 16);   // qz, 1.0
        unsigned w2 = 0x3F80u;                                        // 1.0, 0
        U16 uu;
        uu.u = make_uint4(quad == 0 ? w0 : 0u, quad == 0 ? w1 : 0u,
                          quad == 0 ? w2 : 0u, 0u);
        afrag[mt] = uu.v;
    }
    f32x4 mrow[4];
#pragma unroll
    for (int mt = 0; mt < 4; mt++) mrow[mt] = (f32x4){KNN_INF, KNN_INF, KNN_INF, KNN_INF};
    {
        const uint4* nb = g_nbB + cbase + wid * 512;
        const f32x4 zero = (f32x4){0.f, 0.f, 0.f, 0.f};
#pragma unroll 2
        for (int t = 0; t < 32; t++) {
            uint4 v = nb[t * 16 + l15];
            U16 ub;
            ub.u = make_uint4(quad == 0 ? v.x : 0u, quad == 0 ? v.y : 0u,
                              quad == 0 ? v.z : 0u, 0u);
            bf16x8 bfrag = ub.v;
            f32x4 d0 = __builtin_amdgcn_mfma_f32_16x16x32_bf16(afrag[0], bfrag, zero, 0, 0, 0);
            f32x4 d1 = __builtin_amdgcn_mfma_f32_16x16x32_bf16(afrag[1], bfrag, zero, 0, 0, 0);
            f32x4 d2 = __builtin_amdgcn_mfma_f32_16x16x32_bf16(afrag[2], bfrag, zero, 0, 0, 0);
            f32x4 d3 = __builtin_amdgcn_mfma_f32_16x16x32_bf16(afrag[3], bfrag, zero, 0, 0, 0);
#pragma unroll
            for (int i = 0; i < 4; i++) {
                mrow[0][i] = fminf(mrow[0][i], d0[i]);
                mrow[1][i] = fminf(mrow[1][i], d1[i]);
                mrow[2][i] = fminf(mrow[2][i], d2[i]);
                mrow[3][i] = fminf(mrow[3][i], d3[i]);
            }
        }
    }
#pragma unroll
    for (int mt = 0; mt < 4; mt++) {
#pragma unroll
        for (int r = 0; r < 4; r++) {
            int q = mt * 16 + quad * 4 + r;
            s_part[q * 128 + wid * 16 + l15] = mrow[mt][r];
        }
    }
    __syncthreads();

    // ---- T[r] = 16th-smallest of 64 subset-minima + margin ----
    float T[8];
#pragma unroll
    for (int r = 0; r < 8; r++) {
        int q = wid * 8 + r;
        float v = fminf(s_part[q * 128 + lane], s_part[q * 128 + 64 + lane]);
#pragma unroll
        for (int k = 2; k <= 64; k <<= 1) {
#pragma unroll
            for (int j2 = k >> 1; j2 >= 1; j2 >>= 1) {
                float pv = __shfl_xor(v, j2);
                bool keepMin = (((lane & j2) == 0) == ((lane & k) == 0));
                bool tp = ((pv < v) == keepMin);
                v = tp ? pv : v;
            }
        }
        T[r] = __shfl(v, 15) + margin;
    }

    // ---- scan 2 (trusted fma filter) with dual-threshold validation ----
    int cnt[8], cnts[8];
#pragma unroll
    for (int r = 0; r < 8; r++) { cnt[r] = 0; cnts[r] = 0; }
    for (int ch = 0; ch < 2; ch++) {
        __syncthreads();
        const float4* gp = g_pos4 + cbase + ch * 2048;
        for (int i = threadIdx.x; i < 2048; i += 512) s_c4[i] = gp[i];
        __syncthreads();
        for (int c = 0; c < 32; c++) {
            int jj = c * 64 + lane;
            float4 v4 = s_c4[jj];
#pragma unroll
            for (int r = 0; r < 8; r++) {
                float d = fmaf(v4.z, qz[r], fmaf(v4.y, qy[r], fmaf(v4.x, qx[r], v4.w)));
                bool p = (d <= T[r]);
                unsigned long long mk = __ballot(p);
                if (mk) {
                    int pre = (int)__popcll(mk & ((1ull << lane) - 1ull));
                    int slot = cnt[r] + pre;
                    if (p && slot < 64) s_i[wid][r][slot] = cbase + ch * 2048 + jj;
                    cnt[r] += (int)__popcll(mk);
                    cnts[r] += (int)__popcll(__ballot(d <= T[r] - gap));
                }
            }
        }
    }

    // ---- final: exact unfused d for survivors, (d, idx) bitonic top-16 ----
#pragma unroll
    for (int r = 0; r < 8; r++) {
        int q = qbase + r;
        if (cnt[r] <= 64 && cnts[r] >= 16) {
            int S = cnt[r];
            int idx = (lane < S) ? s_i[wid][r][lane] : 0x7FFFFFFF;
            float d = KNN_INF;
            if (lane < S) {
                float px = g_posf[idx * 3], py = g_posf[idx * 3 + 1], pz = g_posf[idx * 3 + 2];
                float sc = g_scf[idx];
                float dot = px * qx[r] + py * qy[r] + pz * qz[r];
                d = (qs[r] + sc) - 2.0f * dot;
            }
#pragma unroll
            for (int k = 2; k <= 64; k <<= 1) {
#pragma unroll
                for (int j2 = k >> 1; j2 >= 1; j2 >>= 1) {
                    float pd = __shfl_xor(d, j2);
                    int   pi = __shfl_xor(idx, j2);
                    bool keepMin = (((lane & j2) == 0) == ((lane & k) == 0));
                    bool lt = (pd < d) || (pd == d && pi < idx);
                    bool tp = (lt == keepMin);
                    d   = tp ? pd : d;
                    idx = tp ? pi : idx;
                }
            }
            if (lane < 16) {
                g_nbr[q * KNBR + lane] = idx;
                atomicAdd(&g_cnt[idx & (NTOT - 1)], 1);
            }
        } else {
            // exact slow path (T-independent): 16 sequential argmin passes
            float lastd = -KNN_INF; int lasti = -1;
            for (int t = 0; t < 16; t++) {
                float bd = KNN_INF; int bi = 0x7FFFFFFF;
                for (int c = 0; c < 64; c++) {
                    int jj = c * 64 + lane;
                    float px = cp[jj * 3], py = cp[jj * 3 + 1], pz = cp[jj * 3 + 2];
                    float sc = csc[jj];
                    float dot = px * qx[r] + py * qy[r] + pz * qz[r];
                    float dd = (qs[r] + sc) - 2.0f * dot;
                    int gj = cbase + jj;
                    bool after  = (dd > lastd) || (dd == lastd && gj > lasti);
                    bool better = (dd < bd) || (dd == bd && gj < bi);
                    if (after && better) { bd = dd; bi = gj; }
                }
#pragma unroll
                for (int s2 = 1; s2 < 64; s2 <<= 1) {
                    float od = __shfl_xor(bd, s2);
                    int   oi = __shfl_xor(bi, s2);
                    if (od < bd || (od == bd && oi < bi)) { bd = od; bi = oi; }
                }
                if (lane == 0) {
                    g_nbr[q * KNBR + t] = bi;
                    atomicAdd(&g_cnt[bi & (NTOT - 1)], 1);
                }
                lastd = bd; lasti = bi;
            }
        }
    }
}

// ---------------------------------------------------------------------------
// scanA: per-256-block sums of g_cnt
// ---------------------------------------------------------------------------
__global__ __launch_bounds__(256) void scanA_kernel() {
    __shared__ int red[4];
    int t = threadIdx.x, lane = t & 63, w = t >> 6;
    int v = g_cnt[blockIdx.x * 256 + t];
    int s = v;
#pragma unroll
    for (int off = 1; off < 64; off <<= 1) s += __shfl_xor(s, off);
    if (lane == 0) red[w] = s;
    __syncthreads();
    if (t == 0) g_bsum[blockIdx.x] = red[0] + red[1] + red[2] + red[3];
}

// ---------------------------------------------------------------------------
// scanC: each block redundantly sums its prior block-sums, then local scan.
// ---------------------------------------------------------------------------
__global__ __launch_bounds__(256) void scanC_kernel() {
    __shared__ int sred[4];
    __shared__ int wsum[4];
    int t = threadIdx.x, lane = t & 63, w = t >> 6;
    int contrib = (t < 128 && t < blockIdx.x) ? g_bsum[t] : 0;
    int rs = contrib;
#pragma unroll
    for (int off = 1; off < 64; off <<= 1) rs += __shfl_xor(rs, off);
    if (lane == 0) sred[w] = rs;
    __syncthreads();
    int base = sred[0] + sred[1] + sred[2] + sred[3];

    int i = blockIdx.x * 256 + t;
    int v = g_cnt[i];
    int inc = v;
#pragma unroll
    for (int off = 1; off < 64; off <<= 1) {
        int u = __shfl_up(inc, off);
        if (lane >= off) inc += u;
    }
    if (lane == 63) wsum[w] = inc;
    __syncthreads();
    int wbase = 0;
    for (int k = 0; k < w; k++) wbase += wsum[k];
    int excl = base + wbase + inc - v;
    g_offs[i] = excl;
    g_cursor[i] = excl;
    if (i == NTOT - 1) g_offs[NTOT] = E_TOT;
}

__global__ void scatter_kernel() {
    int e = blockIdx.x * 256 + threadIdx.x;
    int c = g_nbr[e] & (NTOT - 1);
    int slot = atomicAdd(&g_cursor[c], 1);
    g_inlist[slot & (E_TOT - 1)] = e;
}

// ---------------------------------------------------------------------------
// Edge kernel (MFMA): unchanged from rounds 4-9 (proven).
// ---------------------------------------------------------------------------
__global__ __launch_bounds__(256) void edge_kernel() {
    __shared__ unsigned short sA[256 * 72];
    __shared__ int scol[256];
    const int t    = threadIdx.x;
    const int lane = t & 63;
    const int w    = t >> 6;
    const int slot0 = blockIdx.x * 256;

    {
        int e = g_inlist[slot0 + t];
        int n = (e >> 4) & (NTOT - 1);
        int j = g_nbr[e] & (NTOT - 1);
        scol[t] = j;
        float dx = g_posf[n * 3 + 0] - g_posf[j * 3 + 0];
        float dy = g_posf[n * 3 + 1] - g_posf[j * 3 + 1];
        float dz = g_posf[n * 3 + 2] - g_posf[j * 3 + 2];
        const unsigned short* b1 = g_base1h + (size_t)n * D_H;
#pragma unroll
        for (int d0 = 0; d0 < D_H; d0 += 8) {
            uint4 p = *(const uint4*)(b1 + d0);
            unsigned pw[4] = {p.x, p.y, p.z, p.w};
            unsigned qw[4];
#pragma unroll
            for (int jp = 0; jp < 4; jp++) {
                int d = d0 + 2 * jp;
                float v0 = __uint_as_float(pw[jp] << 16)
                         + dx * g_Wd[d]     + dy * g_Wd[64 + d]     + dz * g_Wd[128 + d];
                float v1 = __uint_as_float(pw[jp] & 0xFFFF0000u)
                         + dx * g_Wd[d + 1] + dy * g_Wd[64 + d + 1] + dz * g_Wd[128 + d + 1];
                v0 = fmaxf(v0, 0.f); v1 = fmaxf(v1, 0.f);
                qw[jp] = bf16rne(v0) | (bf16rne(v1) << 16);
            }
            *(uint4*)(&sA[t * 72 + d0]) = make_uint4(qw[0], qw[1], qw[2], qw[3]);
        }
    }
    __syncthreads();

    f32x4 acc[4][4];
#pragma unroll
    for (int a = 0; a < 4; a++)
#pragma unroll
        for (int b = 0; b < 4; b++) acc[a][b] = (f32x4){0.f, 0.f, 0.f, 0.f};

    const int quad = lane >> 4;
    const int l15  = lane & 15;
#pragma unroll
    for (int ks = 0; ks < 2; ks++) {
        bf16x8 bfrag[4];
#pragma unroll
        for (int nt = 0; nt < 4; nt++)
            bfrag[nt] = ((const bf16x8*)g_Bfrag)[ks * 256 + nt * 64 + lane];
#pragma unroll
        for (int mt = 0; mt < 4; mt++) {
            int row = w * 64 + mt * 16 + l15;
            bf16x8 afrag = *(const bf16x8*)(&sA[row * 72 + ks * 32 + quad * 8]);
#pragma unroll
            for (int nt = 0; nt < 4; nt++)
                acc[mt][nt] = __builtin_amdgcn_mfma_f32_16x16x32_bf16(afrag, bfrag[nt], acc[mt][nt], 0, 0, 0);
        }
    }
    __syncthreads();

#pragma unroll
    for (int nt = 0; nt < 4; nt++) {
        int dim = nt * 16 + l15;
        float bb = g_fb2v[dim];
#pragma unroll
        for (int mt = 0; mt < 4; mt++) {
#pragma unroll
            for (int r = 0; r < 4; r++) {
                int edge = w * 64 + mt * 16 + quad * 4 + r;
                float v = fmaxf(acc[mt][nt][r] + bb, 0.f);
                sA[edge * 72 + dim] = (unsigned short)bf16rne(v);
            }
        }
    }
    __syncthreads();

    {
        const int ls0 = w * 64;
        const int gs0 = slot0 + ls0;
        int cur = -1;
        float vmax = 0.f;
        for (int s = ls0; s < ls0 + 64; s++) {
            int cj = scol[s];
            float v = b2f(sA[s * 72 + lane]);
            if (cj != cur) {
                if (cur >= 0) {
                    int lo = g_offs[cur], hi = g_offs[cur + 1];
                    if (lo >= gs0 && hi <= gs0 + 64)
                        g_agg[(size_t)cur * D_H + lane] = vmax;
                    else
                        atomicMax((unsigned*)&g_agg[(size_t)cur * D_H + lane], __float_as_uint(vmax));
                }
                cur = cj; vmax = v;
            } else {
                vmax = fmaxf(vmax, v);
            }
        }
        if (cur >= 0) {
            int lo = g_offs[cur], hi = g_offs[cur + 1];
            if (lo >= gs0 && hi <= gs0 + 64)
                g_agg[(size_t)cur * D_H + lane] = vmax;
            else
                atomicMax((unsigned*)&g_agg[(size_t)cur * D_H + lane], __float_as_uint(vmax));
        }
    }
}

// ---------------------------------------------------------------------------
// outmisc: blocks 0..2047 = out (relu(agg @ gW + gb)); 2048.. = pos/batch copy
// ---------------------------------------------------------------------------
__global__ __launch_bounds__(256) void outmisc_kernel(const void* __restrict__ x,
                                                      const void* __restrict__ gW,
                                                      const void* __restrict__ gb,
                                                      const int* __restrict__ batch,
                                                      const void* __restrict__ pos,
                                                      void* __restrict__ out) {
    const int bf = wave_probe(x);
    const int b = blockIdx.x;
    if (b < 2048) {
        int t = threadIdx.x, d = t & 127, half = t >> 7;
        float gcol[D_H];
#pragma unroll
        for (int k = 0; k < D_H; k++) gcol[k] = ldf(gW, k * D_OUT + d, bf);
        float bb = ldf(gb, d, bf);
        int n0 = b * 16 + half * 8;
        for (int r = 0; r < 8; r++) {
            int n = n0 + r;
            float acc = bb;
#pragma unroll
            for (int k = 0; k < D_H; k++) acc += g_agg[(size_t)n * D_H + k] * gcol[k];
            stf(out, n * D_OUT + d, fmaxf(acc, 0.f), bf);
        }
    } else {
        int i = (b - 2048) * 256 + threadIdx.x;
        if (bf) {
            if (i < NTOT * 3) ((unsigned short*)out)[OUT1_OFF + i] = ((const unsigned short*)pos)[i];
            if (i < NTOT)     ((unsigned short*)out)[OUT2_OFF + i] = (unsigned short)bf16rne((float)batch[i]);
        } else {
            if (i < NTOT * 3) ((float*)out)[OUT1_OFF + i] = ((const float*)pos)[i];
            if (i < NTOT)     ((float*)out)[OUT2_OFF + i] = (float)batch[i];
        }
    }
}

// ---------------------------------------------------------------------------
extern "C" void kernel_launch(void* const* d_in, const int* in_sizes, int n_in,
                              void* d_out, int out_size, void* d_ws, size_t ws_size,
                              hipStream_t stream) {
    const void* x     = d_in[0];
    const void* pos   = d_in[1];
    const int*  batch = (const int*)d_in[2];
    const void* fW1   = d_in[3];
    const void* fb1   = d_in[4];
    const void* fW2   = d_in[5];
    const void* fb2   = d_in[6];
    const void* gW    = d_in[7];
    const void* gb    = d_in[8];

    hipLaunchKernelGGL(prep_kernel,    dim3(2049),        dim3(256), 0, stream, x, pos, fW1, fb1, fW2, fb2);
    hipLaunchKernelGGL(knn_kernel,     dim3(NTOT / 64),   dim3(512), 0, stream);
    hipLaunchKernelGGL(scanA_kernel,   dim3(NTOT / 256),  dim3(256), 0, stream);
    hipLaunchKernelGGL(scanC_kernel,   dim3(NTOT / 256),  dim3(256), 0, stream);
    hipLaunchKernelGGL(scatter_kernel, dim3(E_TOT / 256), dim3(256), 0, stream);
    hipLaunchKernelGGL(edge_kernel,    dim3(E_TOT / 256), dim3(256), 0, stream);
    hipLaunchKernelGGL(outmisc_kernel, dim3(2048 + (NTOT * 3 + 255) / 256), dim3(256), 0, stream,
                       x, gW, gb, batch, pos, d_out);
}

// Round 11
// 271.980 us; speedup vs baseline: 1.7706x; 1.7706x over previous
//
#include <hip/hip_runtime.h>
#include <hip/hip_bf16.h>

// Problem constants (fixed by reference)
#define N_PER    4096
#define KNBR     16
#define NTOT     32768
#define D_IN     32
#define D_H      64
#define D_OUT    128
#define E_TOT    (NTOT * KNBR)            // 524288

#define OUT1_OFF (NTOT * D_OUT)           // pos output offset (elements)
#define OUT2_OFF (NTOT * D_OUT + NTOT*3)  // batch output offset (elements)

#define KNN_INF 3.4e38f

typedef __attribute__((ext_vector_type(8))) short bf16x8;   // MFMA A/B frag
typedef __attribute__((ext_vector_type(4))) float f32x4;    // MFMA C/D frag

// ---------------------------------------------------------------------------
// Static device scratch; every buffer fully (re)written each call.
// (Round-11: exact revert to the round-8 structure — the MFMA scan1 of
// rounds 9/10 produced a broken T; round-10's guard proved it via the
// slow-path blowup. knn fma scan1 is proven fast (69us) and exact.)
// ---------------------------------------------------------------------------
__device__ float          g_posf[NTOT * 3];       // f32 pos (exact bf16 upconvert)
__device__ float          g_scf[NTOT];            // per-node |p|^2 (unfused, = numpy sq)
__device__ float4         g_pos4[NTOT];           // {-2px,-2py,-2pz, |p|^2} packed
__device__ int            g_nbr[E_TOT];
__device__ unsigned short g_base1h[NTOT * D_H];   // bf16 base1
__device__ uint4          g_Bfrag[2 * 4 * 64];    // W2 B-fragments [ks][nt][lane]
__device__ float          g_Wd[3 * D_H];
__device__ float          g_fb2v[D_H];
__device__ int            g_cnt[NTOT];
__device__ int            g_bsum[NTOT / 256];     // per-block cnt sums (scan)
__device__ int            g_offs[NTOT + 1];
__device__ int            g_cursor[NTOT];
__device__ int            g_inlist[E_TOT];
__device__ float          g_agg[NTOT * D_H];      // zero-inited (atomicMax targets)

__device__ __forceinline__ float ldf(const void* p, int i, int bf) {
    if (bf) return __uint_as_float(((unsigned)((const unsigned short*)p)[i]) << 16);
    return ((const float*)p)[i];
}
__device__ __forceinline__ unsigned bf16rne(float f) {
    unsigned u = __float_as_uint(f);
    return (u + 0x7FFFu + ((u >> 16) & 1u)) >> 16;
}
__device__ __forceinline__ void stf(void* p, int i, float v, int bf) {
    if (bf) ((unsigned short*)p)[i] = (unsigned short)bf16rne(v);
    else    ((float*)p)[i] = v;
}
__device__ __forceinline__ float b2f(unsigned short h) {
    return __uint_as_float(((unsigned)h) << 16);
}
// Inline dtype probe: majority vote over 64 words of a float tensor. For
// bf16-pair words bits 14:7 are a bf16 exponent (hit ~100%); for f32 they
// are mantissa bits (hit ~12%). 64 samples -> error prob ~0.
__device__ __forceinline__ int wave_probe(const void* x) {
    unsigned wv = ((const unsigned*)x)[threadIdx.x & 63];
    unsigned e = (wv >> 7) & 0xFFu;
    unsigned long long mk = __ballot(e >= 110u && e <= 140u);
    return (__popcll(mk) >= 32) ? 1 : 0;
}

// ---------------------------------------------------------------------------
// prep: blocks 0..1023    = pos->f32, |p|^2, packed {-2p, sc}, zero cnt/agg
//       blocks 1024..2047 = base1[n][d] (vectorized dual-dtype x loads)
//       block  2048       = stage edge-kernel weights (Wd, fb2, W2 B-frags)
// ---------------------------------------------------------------------------
__global__ __launch_bounds__(256) void prep_kernel(const void* __restrict__ x,
                                                   const void* __restrict__ pos,
                                                   const void* __restrict__ fW1,
                                                   const void* __restrict__ fb1,
                                                   const void* __restrict__ fW2,
                                                   const void* __restrict__ fb2) {
    const int bf = wave_probe(x);
    const int b = blockIdx.x;
    if (b < 1024) {
        const int i0 = b * 256 + threadIdx.x;
        const int stride = 1024 * 256;
        for (int i = i0; i < NTOT * 3; i += stride) g_posf[i] = ldf(pos, i, bf);
        {
#pragma clang fp contract(off)
            for (int i = i0; i < NTOT; i += stride) {
                float a = ldf(pos, i * 3 + 0, bf);
                float c2 = ldf(pos, i * 3 + 1, bf);
                float c3 = ldf(pos, i * 3 + 2, bf);
                float sc = a * a + c2 * c2 + c3 * c3;
                g_scf[i] = sc;
                g_pos4[i] = make_float4(-2.0f * a, -2.0f * c2, -2.0f * c3, sc);
                g_cnt[i] = 0;
            }
        }
        for (int i = i0; i < NTOT * D_H; i += stride) g_agg[i] = 0.0f;
    } else if (b < 2048) {
        int lane = threadIdx.x & 63, wid = threadIdx.x >> 6;
        int n0 = (b - 1024) * 32 + wid * 8;
        float wcol[D_IN];
#pragma unroll
        for (int k = 0; k < D_IN; k++) wcol[k] = ldf(fW1, k * D_H + lane, bf);
        float bb = ldf(fb1, lane, bf);
        if (bf) {
            const unsigned short* xp = (const unsigned short*)x;
            for (int r = 0; r < 8; r++) {
                int n = n0 + r;
                const uint4* xr = (const uint4*)(xp + (size_t)n * D_IN);  // 32 bf16 = 4x uint4
                float acc = bb;
#pragma unroll
                for (int q4 = 0; q4 < 4; q4++) {
                    uint4 w4 = xr[q4];
                    unsigned ww[4] = {w4.x, w4.y, w4.z, w4.w};
#pragma unroll
                    for (int p = 0; p < 4; p++) {
                        int k = q4 * 8 + p * 2;
                        acc += __uint_as_float(ww[p] << 16) * wcol[k];
                        acc += __uint_as_float(ww[p] & 0xFFFF0000u) * wcol[k + 1];
                    }
                }
                g_base1h[(size_t)n * D_H + lane] = (unsigned short)bf16rne(acc);
            }
        } else {
            const float* xp = (const float*)x;
            for (int r = 0; r < 8; r++) {
                int n = n0 + r;
                const float4* xr = (const float4*)(xp + (size_t)n * D_IN);
                float acc = bb;
#pragma unroll
                for (int q4 = 0; q4 < 8; q4++) {
                    float4 w4 = xr[q4];
                    int k = q4 * 4;
                    acc += w4.x * wcol[k] + w4.y * wcol[k + 1] + w4.z * wcol[k + 2] + w4.w * wcol[k + 3];
                }
                g_base1h[(size_t)n * D_H + lane] = (unsigned short)bf16rne(acc);
            }
        }
    } else {
        for (int t = threadIdx.x; t < 3 * D_H; t += 256) g_Wd[t] = ldf(fW1, D_IN * D_H + t, bf);
        if (threadIdx.x < D_H) g_fb2v[threadIdx.x] = ldf(fb2, threadIdx.x, bf);
        for (int idx = threadIdx.x; idx < 512; idx += 256) {
            int lane = idx & 63, nt = (idx >> 6) & 3, ks = idx >> 8;
            int n = nt * 16 + (lane & 15);
            int k0 = ks * 32 + ((lane >> 4) << 3);
            unsigned wds[4];
#pragma unroll
            for (int jp = 0; jp < 4; jp++) {
                unsigned lo = bf16rne(ldf(fW2, (k0 + 2 * jp) * D_H + n, bf));
                unsigned hi = bf16rne(ldf(fW2, (k0 + 2 * jp + 1) * D_H + n, bf));
                wds[jp] = lo | (hi << 16);
            }
            g_Bfrag[idx] = make_uint4(wds[0], wds[1], wds[2], wds[3]);
        }
    }
}

// ---------------------------------------------------------------------------
// KNN + fused in-degree count. 512 threads (8 waves, 64 queries) per block;
// candidates staged in 2048-wide float4 chunks ({-2p, sc}, 32 KB LDS).
// Shifted-distance trick: track d' = sc - 2*dot (qs[r] folded out; ordering
// per query preserved since qs is a per-query constant). 3 fma + 1 min /pair.
//  scan1 (fma): per-lane min d' -> T' = 16th-smallest lane min + 1e-3 margin.
//  scan2 (same fma formula): compact indices with d' <= T'. Pigeonhole with
//  identical formulas guarantees >= 16 survivors; margin >> 2*fp32eps
//  guarantees every exact-top-16 candidate survives.
//  final: exact unfused d recomputed for survivors; (d, idx) bitonic sort
//  (bit-identical to rounds 4-8). Exact slow path if > 64 survivors.
// ---------------------------------------------------------------------------
__global__ __launch_bounds__(512) void knn_kernel() {
#pragma clang fp contract(off)
    __shared__ float4 s_c4[2048];
    __shared__ int s_i[8][8][64];
    const int lane = threadIdx.x & 63;
    const int wid  = threadIdx.x >> 6;
    const int qbase = blockIdx.x * 64 + wid * 8;
    const int cbase = (qbase >> 12) << 12;
    const float* cp  = g_posf + cbase * 3;
    const float* csc = g_scf + cbase;

    float qx[8], qy[8], qz[8], qs[8];
#pragma unroll
    for (int r = 0; r < 8; r++) {
        qx[r] = g_posf[(qbase + r) * 3 + 0];
        qy[r] = g_posf[(qbase + r) * 3 + 1];
        qz[r] = g_posf[(qbase + r) * 3 + 2];
        qs[r] = g_scf[qbase + r];
    }

    // ---- scan 1 (fma, shifted d', bound only) ----
    float m[8];
#pragma unroll
    for (int r = 0; r < 8; r++) m[r] = KNN_INF;
    for (int ch = 0; ch < 2; ch++) {
        __syncthreads();
        const float4* gp = g_pos4 + cbase + ch * 2048;
        for (int i = threadIdx.x; i < 2048; i += 512) s_c4[i] = gp[i];
        __syncthreads();
#pragma unroll 4
        for (int c = 0; c < 32; c++) {
            float4 v4 = s_c4[c * 64 + lane];
#pragma unroll
            for (int r = 0; r < 8; r++) {
                float d = fmaf(v4.z, qz[r], fmaf(v4.y, qy[r], fmaf(v4.x, qx[r], v4.w)));
                m[r] = fminf(m[r], d);
            }
        }
    }

    // ---- T'[r] = 16th smallest lane-min + margin ----
    float T[8];
#pragma unroll
    for (int r = 0; r < 8; r++) {
        float v = m[r];
#pragma unroll
        for (int k = 2; k <= 64; k <<= 1) {
#pragma unroll
            for (int j2 = k >> 1; j2 >= 1; j2 >>= 1) {
                float pv = __shfl_xor(v, j2);
                bool keepMin = (((lane & j2) == 0) == ((lane & k) == 0));
                bool tp = ((pv < v) == keepMin);
                v = tp ? pv : v;
            }
        }
        T[r] = __shfl(v, 15) + 1e-3f;
    }

    // ---- scan 2 (same fma formula, compact indices only) ----
    int cnt[8];
#pragma unroll
    for (int r = 0; r < 8; r++) cnt[r] = 0;
    for (int ch = 0; ch < 2; ch++) {
        __syncthreads();
        const float4* gp = g_pos4 + cbase + ch * 2048;
        for (int i = threadIdx.x; i < 2048; i += 512) s_c4[i] = gp[i];
        __syncthreads();
        for (int c = 0; c < 32; c++) {
            int jj = c * 64 + lane;
            float4 v4 = s_c4[jj];
#pragma unroll
            for (int r = 0; r < 8; r++) {
                float d = fmaf(v4.z, qz[r], fmaf(v4.y, qy[r], fmaf(v4.x, qx[r], v4.w)));
                bool p = (d <= T[r]);
                unsigned long long mk = __ballot(p);
                if (mk) {
                    int pre = (int)__popcll(mk & ((1ull << lane) - 1ull));
                    int slot = cnt[r] + pre;
                    if (p && slot < 64) s_i[wid][r][slot] = cbase + ch * 2048 + jj;
                    cnt[r] += (int)__popcll(mk);
                }
            }
        }
    }

    // ---- final: exact unfused d for survivors, (d, idx) bitonic top-16 ----
#pragma unroll
    for (int r = 0; r < 8; r++) {
        int q = qbase + r;
        if (cnt[r] <= 64) {
            int S = cnt[r];
            int idx = (lane < S) ? s_i[wid][r][lane] : 0x7FFFFFFF;
            float d = KNN_INF;
            if (lane < S) {
                float px = g_posf[idx * 3], py = g_posf[idx * 3 + 1], pz = g_posf[idx * 3 + 2];
                float sc = g_scf[idx];
                float dot = px * qx[r] + py * qy[r] + pz * qz[r];
                d = (qs[r] + sc) - 2.0f * dot;
            }
#pragma unroll
            for (int k = 2; k <= 64; k <<= 1) {
#pragma unroll
                for (int j2 = k >> 1; j2 >= 1; j2 >>= 1) {
                    float pd = __shfl_xor(d, j2);
                    int   pi = __shfl_xor(idx, j2);
                    bool keepMin = (((lane & j2) == 0) == ((lane & k) == 0));
                    bool lt = (pd < d) || (pd == d && pi < idx);
                    bool tp = (lt == keepMin);
                    d   = tp ? pd : d;
                    idx = tp ? pi : idx;
                }
            }
            if (lane < 16) {
                g_nbr[q * KNBR + lane] = idx;
                atomicAdd(&g_cnt[idx & (NTOT - 1)], 1);
            }
        } else {
            // exact slow path: 16 sequential argmin passes over global pos
            float lastd = -KNN_INF; int lasti = -1;
            for (int t = 0; t < 16; t++) {
                float bd = KNN_INF; int bi = 0x7FFFFFFF;
                for (int c = 0; c < 64; c++) {
                    int jj = c * 64 + lane;
                    float px = cp[jj * 3], py = cp[jj * 3 + 1], pz = cp[jj * 3 + 2];
                    float sc = csc[jj];
                    float dot = px * qx[r] + py * qy[r] + pz * qz[r];
                    float dd = (qs[r] + sc) - 2.0f * dot;
                    int gj = cbase + jj;
                    bool after  = (dd > lastd) || (dd == lastd && gj > lasti);
                    bool better = (dd < bd) || (dd == bd && gj < bi);
                    if (after && better) { bd = dd; bi = gj; }
                }
#pragma unroll
                for (int s2 = 1; s2 < 64; s2 <<= 1) {
                    float od = __shfl_xor(bd, s2);
                    int   oi = __shfl_xor(bi, s2);
                    if (od < bd || (od == bd && oi < bi)) { bd = od; bi = oi; }
                }
                if (lane == 0) {
                    g_nbr[q * KNBR + t] = bi;
                    atomicAdd(&g_cnt[bi & (NTOT - 1)], 1);
                }
                lastd = bd; lasti = bi;
            }
        }
    }
}

// ---------------------------------------------------------------------------
// scanA: per-256-block sums of g_cnt
// ---------------------------------------------------------------------------
__global__ __launch_bounds__(256) void scanA_kernel() {
    __shared__ int red[4];
    int t = threadIdx.x, lane = t & 63, w = t >> 6;
    int v = g_cnt[blockIdx.x * 256 + t];
    int s = v;
#pragma unroll
    for (int off = 1; off < 64; off <<= 1) s += __shfl_xor(s, off);
    if (lane == 0) red[w] = s;
    __syncthreads();
    if (t == 0) g_bsum[blockIdx.x] = red[0] + red[1] + red[2] + red[3];
}

// ---------------------------------------------------------------------------
// scanC: each block redundantly sums its prior block-sums, then local scan.
// ---------------------------------------------------------------------------
__global__ __launch_bounds__(256) void scanC_kernel() {
    __shared__ int sred[4];
    __shared__ int wsum[4];
    int t = threadIdx.x, lane = t & 63, w = t >> 6;
    int contrib = (t < 128 && t < blockIdx.x) ? g_bsum[t] : 0;
    int rs = contrib;
#pragma unroll
    for (int off = 1; off < 64; off <<= 1) rs += __shfl_xor(rs, off);
    if (lane == 0) sred[w] = rs;
    __syncthreads();
    int base = sred[0] + sred[1] + sred[2] + sred[3];

    int i = blockIdx.x * 256 + t;
    int v = g_cnt[i];
    int inc = v;
#pragma unroll
    for (int off = 1; off < 64; off <<= 1) {
        int u = __shfl_up(inc, off);
        if (lane >= off) inc += u;
    }
    if (lane == 63) wsum[w] = inc;
    __syncthreads();
    int wbase = 0;
    for (int k = 0; k < w; k++) wbase += wsum[k];
    int excl = base + wbase + inc - v;
    g_offs[i] = excl;
    g_cursor[i] = excl;
    if (i == NTOT - 1) g_offs[NTOT] = E_TOT;
}

__global__ void scatter_kernel() {
    int e = blockIdx.x * 256 + threadIdx.x;
    int c = g_nbr[e] & (NTOT - 1);
    int slot = atomicAdd(&g_cursor[c], 1);
    g_inlist[slot & (E_TOT - 1)] = e;
}

// ---------------------------------------------------------------------------
// Edge kernel (MFMA): unchanged from rounds 4-10 (proven).
// ---------------------------------------------------------------------------
__global__ __launch_bounds__(256) void edge_kernel() {
    __shared__ unsigned short sA[256 * 72];
    __shared__ int scol[256];
    const int t    = threadIdx.x;
    const int lane = t & 63;
    const int w    = t >> 6;
    const int slot0 = blockIdx.x * 256;

    // ---- phase 1: h1 for this thread's edge ----
    {
        int e = g_inlist[slot0 + t];
        int n = (e >> 4) & (NTOT - 1);
        int j = g_nbr[e] & (NTOT - 1);
        scol[t] = j;
        float dx = g_posf[n * 3 + 0] - g_posf[j * 3 + 0];
        float dy = g_posf[n * 3 + 1] - g_posf[j * 3 + 1];
        float dz = g_posf[n * 3 + 2] - g_posf[j * 3 + 2];
        const unsigned short* b1 = g_base1h + (size_t)n * D_H;
#pragma unroll
        for (int d0 = 0; d0 < D_H; d0 += 8) {
            uint4 p = *(const uint4*)(b1 + d0);
            unsigned pw[4] = {p.x, p.y, p.z, p.w};
            unsigned qw[4];
#pragma unroll
            for (int jp = 0; jp < 4; jp++) {
                int d = d0 + 2 * jp;
                float v0 = __uint_as_float(pw[jp] << 16)
                         + dx * g_Wd[d]     + dy * g_Wd[64 + d]     + dz * g_Wd[128 + d];
                float v1 = __uint_as_float(pw[jp] & 0xFFFF0000u)
                         + dx * g_Wd[d + 1] + dy * g_Wd[64 + d + 1] + dz * g_Wd[128 + d + 1];
                v0 = fmaxf(v0, 0.f); v1 = fmaxf(v1, 0.f);
                qw[jp] = bf16rne(v0) | (bf16rne(v1) << 16);
            }
            *(uint4*)(&sA[t * 72 + d0]) = make_uint4(qw[0], qw[1], qw[2], qw[3]);
        }
    }
    __syncthreads();

    // ---- phase 2: MFMA h2 = h1 @ W2 ----
    f32x4 acc[4][4];
#pragma unroll
    for (int a = 0; a < 4; a++)
#pragma unroll
        for (int b = 0; b < 4; b++) acc[a][b] = (f32x4){0.f, 0.f, 0.f, 0.f};

    const int quad = lane >> 4;
    const int l15  = lane & 15;
#pragma unroll
    for (int ks = 0; ks < 2; ks++) {
        bf16x8 bfrag[4];
#pragma unroll
        for (int nt = 0; nt < 4; nt++)
            bfrag[nt] = ((const bf16x8*)g_Bfrag)[ks * 256 + nt * 64 + lane];
#pragma unroll
        for (int mt = 0; mt < 4; mt++) {
            int row = w * 64 + mt * 16 + l15;
            bf16x8 afrag = *(const bf16x8*)(&sA[row * 72 + ks * 32 + quad * 8]);
#pragma unroll
            for (int nt = 0; nt < 4; nt++)
                acc[mt][nt] = __builtin_amdgcn_mfma_f32_16x16x32_bf16(afrag, bfrag[nt], acc[mt][nt], 0, 0, 0);
        }
    }
    __syncthreads();

    // ---- phase 3a: relu(h2 + b2) -> LDS bf16 ----
#pragma unroll
    for (int nt = 0; nt < 4; nt++) {
        int dim = nt * 16 + l15;
        float bb = g_fb2v[dim];
#pragma unroll
        for (int mt = 0; mt < 4; mt++) {
#pragma unroll
            for (int r = 0; r < 4; r++) {
                int edge = w * 64 + mt * 16 + quad * 4 + r;
                float v = fmaxf(acc[mt][nt][r] + bb, 0.f);
                sA[edge * 72 + dim] = (unsigned short)bf16rne(v);
            }
        }
    }
    __syncthreads();

    // ---- phase 3b: segmented run-max, lane = dim ----
    {
        const int ls0 = w * 64;
        const int gs0 = slot0 + ls0;
        int cur = -1;
        float vmax = 0.f;
        for (int s = ls0; s < ls0 + 64; s++) {
            int cj = scol[s];
            float v = b2f(sA[s * 72 + lane]);
            if (cj != cur) {
                if (cur >= 0) {
                    int lo = g_offs[cur], hi = g_offs[cur + 1];
                    if (lo >= gs0 && hi <= gs0 + 64)
                        g_agg[(size_t)cur * D_H + lane] = vmax;
                    else
                        atomicMax((unsigned*)&g_agg[(size_t)cur * D_H + lane], __float_as_uint(vmax));
                }
                cur = cj; vmax = v;
            } else {
                vmax = fmaxf(vmax, v);
            }
        }
        if (cur >= 0) {
            int lo = g_offs[cur], hi = g_offs[cur + 1];
            if (lo >= gs0 && hi <= gs0 + 64)
                g_agg[(size_t)cur * D_H + lane] = vmax;
            else
                atomicMax((unsigned*)&g_agg[(size_t)cur * D_H + lane], __float_as_uint(vmax));
        }
    }
}

// ---------------------------------------------------------------------------
// outmisc: blocks 0..2047 = out (relu(agg @ gW + gb)); 2048.. = pos/batch copy
// ---------------------------------------------------------------------------
__global__ __launch_bounds__(256) void outmisc_kernel(const void* __restrict__ x,
                                                      const void* __restrict__ gW,
                                                      const void* __restrict__ gb,
                                                      const int* __restrict__ batch,
                                                      const void* __restrict__ pos,
                                                      void* __restrict__ out) {
    const int bf = wave_probe(x);
    const int b = blockIdx.x;
    if (b < 2048) {
        int t = threadIdx.x, d = t & 127, half = t >> 7;
        float gcol[D_H];
#pragma unroll
        for (int k = 0; k < D_H; k++) gcol[k] = ldf(gW, k * D_OUT + d, bf);
        float bb = ldf(gb, d, bf);
        int n0 = b * 16 + half * 8;
        for (int r = 0; r < 8; r++) {
            int n = n0 + r;
            float acc = bb;
#pragma unroll
            for (int k = 0; k < D_H; k++) acc += g_agg[(size_t)n * D_H + k] * gcol[k];
            stf(out, n * D_OUT + d, fmaxf(acc, 0.f), bf);
        }
    } else {
        int i = (b - 2048) * 256 + threadIdx.x;
        if (bf) {
            if (i < NTOT * 3) ((unsigned short*)out)[OUT1_OFF + i] = ((const unsigned short*)pos)[i];
            if (i < NTOT)     ((unsigned short*)out)[OUT2_OFF + i] = (unsigned short)bf16rne((float)batch[i]);
        } else {
            if (i < NTOT * 3) ((float*)out)[OUT1_OFF + i] = ((const float*)pos)[i];
            if (i < NTOT)     ((float*)out)[OUT2_OFF + i] = (float)batch[i];
        }
    }
}

// ---------------------------------------------------------------------------
extern "C" void kernel_launch(void* const* d_in, const int* in_sizes, int n_in,
                              void* d_out, int out_size, void* d_ws, size_t ws_size,
                              hipStream_t stream) {
    const void* x     = d_in[0];
    const void* pos   = d_in[1];
    const int*  batch = (const int*)d_in[2];
    const void* fW1   = d_in[3];
    const void* fb1   = d_in[4];
    const void* fW2   = d_in[5];
    const void* fb2   = d_in[6];
    const void* gW    = d_in[7];
    const void* gb    = d_in[8];

    hipLaunchKernelGGL(prep_kernel,    dim3(2049),        dim3(256), 0, stream, x, pos, fW1, fb1, fW2, fb2);
    hipLaunchKernelGGL(knn_kernel,     dim3(NTOT / 64),   dim3(512), 0, stream);
    hipLaunchKernelGGL(scanA_kernel,   dim3(NTOT / 256),  dim3(256), 0, stream);
    hipLaunchKernelGGL(scanC_kernel,   dim3(NTOT / 256),  dim3(256), 0, stream);
    hipLaunchKernelGGL(scatter_kernel, dim3(E_TOT / 256), dim3(256), 0, stream);
    hipLaunchKernelGGL(edge_kernel,    dim3(E_TOT / 256), dim3(256), 0, stream);
    hipLaunchKernelGGL(outmisc_kernel, dim3(2048 + (NTOT * 3 + 255) / 256), dim3(256), 0, stream,
                       x, gW, gb, batch, pos, d_out);
}